// Round 11
// baseline (337.583 us; speedup 1.0000x reference)
//
#include <hip/hip_runtime.h>
#include <hip/hip_fp16.h>

#define NPTS  2048
#define BATCH 4
#define NBP   8192      // BATCH*NPTS
#define MROWS 24576     // NBP*3
#define KNN_K 16

typedef short bf16x8 __attribute__((ext_vector_type(8)));
typedef float f32x4  __attribute__((ext_vector_type(4)));

// split fp32 into bf16 hi + bf16 lo (RTNE), x ~= hi + lo to ~2^-17 rel
static __device__ __forceinline__ void split_bf16(float a, unsigned short& h, unsigned short& l)
{
    unsigned u = __float_as_uint(a);
    unsigned hr = (u + 0x7FFFu + ((u >> 16) & 1u)) & 0xFFFF0000u;
    h = (unsigned short)(hr >> 16);
    float rem = a - __uint_as_float(hr);
    unsigned v = __float_as_uint(rem);
    l = (unsigned short)((v + 0x7FFFu + ((v >> 16) & 1u)) >> 16);
}

static __device__ __forceinline__ float bf2(unsigned short h, unsigned short l)
{
    return __uint_as_float((unsigned)h << 16) + __uint_as_float((unsigned)l << 16);
}

static __device__ __forceinline__ unsigned long long shfl_xor_u64(unsigned long long v, int mask)
{
    unsigned lo = (unsigned)v, hi = (unsigned)(v >> 32);
    lo = (unsigned)__shfl_xor((int)lo, mask, 64);
    hi = (unsigned)__shfl_xor((int)hi, mask, 64);
    return ((unsigned long long)hi << 32) | lo;
}

// XCD-confinement swizzle (bijection; wrong mapping assumption = speed-neutral)
static __device__ __forceinline__ int xcd_swizzle(int i, int G)
{
    int batch  = (i >> 1) & 3;
    int within = ((i >> 3) << 1) | (i & 1);
    return batch * (G >> 2) + within;
}

// interleaved edge-weight element: rows j<2O: AF0 AD0 AF1 AD1...; j>=2O: GF0 GD0...
static __device__ __forceinline__ float wbig_val(const float* __restrict__ Wf,
                                                 const float* __restrict__ Wd,
                                                 int j, int c, int O, int C)
{
    if (j < 2 * O) {
        int o = j >> 1;
        return (j & 1) ? Wd[o * 2 * C + c] : Wf[o * 2 * C + c];
    }
    int o = (j - 2 * O) >> 1;
    return (j & 1) ? (Wd[o * 2 * C + C + c] - Wd[o * 2 * C + c])
                   : (Wf[o * 2 * C + C + c] - Wf[o * 2 * C + c]);
}

// ---------------------------------------------------------------------------
// prep mega-kernel: layer-1 (K=1 GEMM straight from x) + all weight builds
// ---------------------------------------------------------------------------
#define PC0 1572864          // l1: MROWS*64 -> AH/AG
#define PC1 (PC0 + 4096)     // Wb2 (O=32,C=16,Kp=32)
#define PC2 (PC1 + 8192)     // Wb3 (O=64,C=32,Kp=32)
#define PC3 (PC2 + 32768)    // Wb4 (O=128,C=64,Kp=64)
#define PC4 (PC3 + 49152)    // Wc stack (192 x 256)
#define PC5 (PC4 + 65536)    // Wi1 stack (256 x 256)
#define PC6 (PC5 + 65536)    // Wi2 stack (512 x 128)

__global__ __launch_bounds__(256) void prep_kernel(
    const float* __restrict__ x, __half* __restrict__ AH, float* __restrict__ AG,
    const float* __restrict__ w1f, const float* __restrict__ w1d,
    const float* __restrict__ w2f, const float* __restrict__ w2d,
    unsigned short* __restrict__ Wb2h, unsigned short* __restrict__ Wb2l,
    const float* __restrict__ w3f, const float* __restrict__ w3d,
    unsigned short* __restrict__ Wb3h, unsigned short* __restrict__ Wb3l,
    const float* __restrict__ w4f, const float* __restrict__ w4d,
    unsigned short* __restrict__ Wb4h, unsigned short* __restrict__ Wb4l,
    const float* __restrict__ wcf, const float* __restrict__ wcd,
    unsigned short* __restrict__ Wch, unsigned short* __restrict__ Wcl,
    const float* __restrict__ wi1f, const float* __restrict__ wi1d,
    unsigned short* __restrict__ Wi1h, unsigned short* __restrict__ Wi1l,
    const float* __restrict__ wi2f, const float* __restrict__ wi2d,
    unsigned short* __restrict__ Wi2h, unsigned short* __restrict__ Wi2l)
{
    int i = blockIdx.x * 256 + threadIdx.x;
    if (i < PC0) {
        // layer-1: out[row, o] = x_row * Wb1[o]  (interleaved A|G split)
        int o = i & 63;
        int row = i >> 6;
        int v = row % 3;
        int gp = row / 3;
        int b = gp >> 11;
        int n = gp & (NPTS - 1);
        float xv = x[(b * 3 + v) * NPTS + n];
        float wv = wbig_val(w1f, w1d, o, 0, 16, 1);
        float val = xv * wv;
        if (o < 32) AH[(size_t)row * 32 + o] = __float2half(val);
        else        AG[(size_t)row * 32 + o - 32] = val;
    } else if (i < PC6) {
        float v = 0.f;
        unsigned short *ph, *pl;
        int ix;
        if (i < PC1) {            // Wb2: O=32,C=16,Kpad=32
            ix = i - PC0;
            int c = ix & 31, j = ix >> 5;
            if (c < 16) v = wbig_val(w2f, w2d, j, c, 32, 16);
            ph = Wb2h; pl = Wb2l;
        } else if (i < PC2) {     // Wb3: O=64,C=32,Kpad=32
            ix = i - PC1;
            int c = ix & 31, j = ix >> 5;
            v = wbig_val(w3f, w3d, j, c, 64, 32);
            ph = Wb3h; pl = Wb3l;
        } else if (i < PC3) {     // Wb4: O=128,C=64,Kpad=64
            ix = i - PC2;
            int c = ix & 63, j = ix >> 6;
            v = wbig_val(w4f, w4d, j, c, 128, 64);
            ph = Wb4h; pl = Wb4l;
        } else if (i < PC4) {     // Wc: stack wcf(128) + wcd(1), K=240, 192x256
            ix = i - PC3;
            int c = ix & 255, r = ix >> 8;
            if (c < 240) {
                if (r < 128) v = wcf[r * 240 + c];
                else if (r < 129) v = wcd[(r - 128) * 240 + c];
            }
            ph = Wch; pl = Wcl;
        } else if (i < PC5) {     // Wi1: stack wi1f(128)+wi1d(128), K=256, 256x256
            ix = i - PC4;
            int c = ix & 255, r = ix >> 8;
            if (r < 128) v = wi1f[r * 256 + c];
            else v = wi1d[(r - 128) * 256 + c];
            ph = Wi1h; pl = Wi1l;
        } else {                  // Wi2: stack wi2f(256)+wi2d(256), K=128, 512x128
            ix = i - PC5;
            int c = ix & 127, r = ix >> 7;
            if (r < 256) v = wi2f[r * 128 + c];
            else v = wi2d[(r - 256) * 128 + c];
            ph = Wi2h; pl = Wi2l;
        }
        unsigned short h, l;
        split_bf16(v, h, l);
        ph[ix] = h; pl[ix] = l;
    }
}

// ---------------------------------------------------------------------------
// KNN v4: one 64-thread block (= one wave) per query; keys in LDS; incremental
// argmin; ONE u64 butterfly per round packing (key<<32)|(slot<<6)|lane so
// min == lexicographic (d2, m) == top_k order.
// ---------------------------------------------------------------------------
__global__ __launch_bounds__(64) void knn_kernel(const float* __restrict__ x, int* __restrict__ idx)
{
    __shared__ unsigned ksh[64 * 34];
    const int t  = threadIdx.x;       // 0..63
    const int bn = blockIdx.x;        // query id
    const int b = bn >> 11;
    const int n = bn & (NPTS - 1);
    const float* xb = x + b * 3 * NPTS;
    const float qx = xb[n], qy = xb[NPTS + n], qz = xb[2 * NPTS + n];
    const float sqn = fmaf(qz, qz, fmaf(qy, qy, qx * qx));
    unsigned* ks = &ksh[t * 34];

    unsigned gm[4];
    int ga[4];
#pragma unroll
    for (int g = 0; g < 4; g++) {
        unsigned kk[8];
#pragma unroll
        for (int j = 0; j < 8; j++) {
            const int i = g * 8 + j;
            const int m = (i << 6) + t;
            float mx = xb[m], my = xb[NPTS + m], mz = xb[2 * NPTS + m];
            float sqm = fmaf(mz, mz, fmaf(my, my, mx * mx));
            float dt  = fmaf(qz, mz, fmaf(qy, my, qx * mx));
            float d2  = sqn + sqm - 2.0f * dt;
            unsigned u = __float_as_uint(d2);
            u ^= (u & 0x80000000u) ? 0xFFFFFFFFu : 0x80000000u;  // monotone map
            kk[j] = u;
        }
        *(uint2*)&ks[g * 8 + 0] = make_uint2(kk[0], kk[1]);
        *(uint2*)&ks[g * 8 + 2] = make_uint2(kk[2], kk[3]);
        *(uint2*)&ks[g * 8 + 4] = make_uint2(kk[4], kk[5]);
        *(uint2*)&ks[g * 8 + 6] = make_uint2(kk[6], kk[7]);
        unsigned bg = kk[0];
        int ba = g * 8;
#pragma unroll
        for (int j = 1; j < 8; j++) {       // ascending + strict < keeps lowest slot on tie
            if (kk[j] < bg) { bg = kk[j]; ba = g * 8 + j; }
        }
        gm[g] = bg; ga[g] = ba;
    }
    unsigned lm = gm[0];
    int il = ga[0];
#pragma unroll
    for (int g = 1; g < 4; g++) if (gm[g] < lm) { lm = gm[g]; il = ga[g]; }

    unsigned long long pk = ((unsigned long long)lm << 32) | (unsigned)((il << 6) | t);
    int res = -1;
    for (int r = 0; r < KNN_K; r++) {
        unsigned long long w = pk;
#pragma unroll
        for (int off = 32; off > 0; off >>= 1) {
            unsigned long long o = shfl_xor_u64(w, off);
            w = (o < w) ? o : w;
        }
        if (t == r) res = (int)(w & 0xFFFFFFFFull);

        if (pk == w) {                    // exactly one owner lane (m unique)
            ks[il] = 0xFFFFFFFFu;         // zap (computed LDS address)
            const int g = il >> 3;
            unsigned bg = ks[g * 8];
            int ba = g * 8;
#pragma unroll
            for (int j = 1; j < 8; j++) {
                unsigned kv = ks[g * 8 + j];
                if (kv < bg) { bg = kv; ba = g * 8 + j; }
            }
            gm[g] = bg; ga[g] = ba;
            lm = gm[0]; il = ga[0];
#pragma unroll
            for (int g2 = 1; g2 < 4; g2++) if (gm[g2] < lm) { lm = gm[g2]; il = ga[g2]; }
            pk = ((unsigned long long)lm << 32) | (unsigned)((il << 6) | t);
        }
    }
    if (t < KNN_K) idx[bn * KNN_K + t] = res;
}

// ---------------------------------------------------------------------------
// Split-bf16 MFMA GEMM (NT), NO LDS: B-frags loaded straight from global
// (W is L2-resident; frag layout row*Kpad+k0+q*8 is native) -> zero barriers
// in the K-loop, compiler pipelines with vmcnt. Same MFMA order as before ->
// bit-identical. Epilogue modes:
//  - OUTA==null: fp32 OUT [m, ldo]
//  - OUTA!=null (edge): col<twoO -> fp16 OUTA [m, twoO]; else fp32 OUTG
// ---------------------------------------------------------------------------
__global__ __launch_bounds__(256) void gemm_mfma(
    const unsigned short* __restrict__ Xh, const unsigned short* __restrict__ Xl,
    int ldx, int xoff,
    const unsigned short* __restrict__ Wh, const unsigned short* __restrict__ Wl,
    float* __restrict__ OUT, int ldo, int Nout, int Kpad,
    __half* __restrict__ OUTA, float* __restrict__ OUTG, int twoO)
{
    const int tid = threadIdx.x;
    const int bm = blockIdx.x * 256;
    const int bo = blockIdx.y * 64;
    const int lane = tid & 63;
    const int wv = tid >> 6;
    const int mr = lane & 15;
    const int q  = lane >> 4;

    f32x4 acc[4][4];
#pragma unroll
    for (int a = 0; a < 4; a++)
#pragma unroll
        for (int c = 0; c < 4; c++) acc[a][c] = (f32x4){0.f, 0.f, 0.f, 0.f};

    for (int k0 = 0; k0 < Kpad; k0 += 32) {
        bf16x8 ah[4], al[4], bh[4], bl[4];
#pragma unroll
        for (int mf = 0; mf < 4; mf++) {
            const size_t xrow = (size_t)(bm + wv * 64 + mf * 16 + mr) * ldx + xoff + k0 + q * 8;
            ah[mf] = *(const bf16x8*)(Xh + xrow);
            al[mf] = *(const bf16x8*)(Xl + xrow);
        }
#pragma unroll
        for (int nf = 0; nf < 4; nf++) {
            const size_t wrow = (size_t)(bo + nf * 16 + mr) * Kpad + k0 + q * 8;
            bh[nf] = *(const bf16x8*)(Wh + wrow);
            bl[nf] = *(const bf16x8*)(Wl + wrow);
        }
#pragma unroll
        for (int mf = 0; mf < 4; mf++)
#pragma unroll
            for (int nf = 0; nf < 4; nf++) {
                acc[mf][nf] = __builtin_amdgcn_mfma_f32_16x16x32_bf16(ah[mf], bh[nf], acc[mf][nf], 0, 0, 0);
                acc[mf][nf] = __builtin_amdgcn_mfma_f32_16x16x32_bf16(ah[mf], bl[nf], acc[mf][nf], 0, 0, 0);
                acc[mf][nf] = __builtin_amdgcn_mfma_f32_16x16x32_bf16(al[mf], bh[nf], acc[mf][nf], 0, 0, 0);
            }
    }

    // epilogue: D layout col=lane&15, row=q*4+i
    if (OUTA) {
#pragma unroll
        for (int nf = 0; nf < 4; nf++) {
            const int col = bo + nf * 16 + mr;
            if (col < twoO) {
#pragma unroll
                for (int mf = 0; mf < 4; mf++)
#pragma unroll
                    for (int i = 0; i < 4; i++) {
                        const int row = bm + wv * 64 + mf * 16 + q * 4 + i;
                        OUTA[(size_t)row * twoO + col] = __float2half(acc[mf][nf][i]);
                    }
            } else {
#pragma unroll
                for (int mf = 0; mf < 4; mf++)
#pragma unroll
                    for (int i = 0; i < 4; i++) {
                        const int row = bm + wv * 64 + mf * 16 + q * 4 + i;
                        OUTG[(size_t)row * twoO + col - twoO] = acc[mf][nf][i];
                    }
            }
        }
    } else {
#pragma unroll
        for (int nf = 0; nf < 4; nf++) {
            const int col = bo + nf * 16 + mr;
            if (col < Nout) {
#pragma unroll
                for (int mf = 0; mf < 4; mf++)
#pragma unroll
                    for (int i = 0; i < 4; i++) {
                        const int row = bm + wv * 64 + mf * 16 + q * 4 + i;
                        OUT[(size_t)row * ldo + col] = acc[mf][nf][i];
                    }
            }
        }
    }
}

// ---------------------------------------------------------------------------
// Fused GEMM + vec_lna (wc / wi1). Block: 4 waves, M-tile 48 rows (16 points),
// N = full width (4 x NF x 16). B-frags straight from global (no W staging,
// no K-loop barriers). If xmh != null, A-frags for k>=128 come from the
// 12x128 xm table (row -> (b,v)); else from Xh/Xl at ld ldx.
// After the K-loop the 48 x NC fp32 PD tile goes to LDS, lna computes
// in-block, writes bf16-pair outputs at ld 128. Bit-identical math.
// WCMODE: d = col 128 (shared); else d = cols 128..255.
// ---------------------------------------------------------------------------
template <int NF, bool WCMODE>
__global__ __launch_bounds__(256, 3) void gemm_lna(
    const unsigned short* __restrict__ Xh, const unsigned short* __restrict__ Xl, int ldx,
    const unsigned short* __restrict__ xmh, const unsigned short* __restrict__ xml,
    const unsigned short* __restrict__ Wh, const unsigned short* __restrict__ Wl,
    int Kpad,
    unsigned short* __restrict__ oh, unsigned short* __restrict__ ol)
{
    constexpr int NC  = NF * 64;       // total output cols
    constexpr int LDT = NC + 1;        // fp32 tile stride
    __shared__ float tb[48 * LDT];

    const int tid = threadIdx.x;
    const int bm = blockIdx.x * 48;
    const int lane = tid & 63;
    const int wv = tid >> 6;
    const int mr = lane & 15;
    const int q  = lane >> 4;

    f32x4 acc[3][NF];
#pragma unroll
    for (int a = 0; a < 3; a++)
#pragma unroll
        for (int c = 0; c < NF; c++) acc[a][c] = (f32x4){0.f, 0.f, 0.f, 0.f};

    for (int k0 = 0; k0 < Kpad; k0 += 32) {
        bf16x8 ah[3], al[3], bh[NF], bl[NF];
#pragma unroll
        for (int mf = 0; mf < 3; mf++) {
            const int row = bm + mf * 16 + mr;
            size_t xrow;
            const unsigned short *sh_, *sl_;
            if (xmh != nullptr && k0 >= 128) {
                const int gp = row / 3;
                const int v = row - gp * 3;
                const int b = gp >> 11;
                xrow = (size_t)(b * 3 + v) * 128 + (k0 - 128) + q * 8;
                sh_ = xmh; sl_ = xml;
            } else {
                xrow = (size_t)row * ldx + k0 + q * 8;
                sh_ = Xh; sl_ = Xl;
            }
            ah[mf] = *(const bf16x8*)(sh_ + xrow);
            al[mf] = *(const bf16x8*)(sl_ + xrow);
        }
#pragma unroll
        for (int nf = 0; nf < NF; nf++) {
            const size_t wrow = (size_t)(wv * 16 * NF + nf * 16 + mr) * Kpad + k0 + q * 8;
            bh[nf] = *(const bf16x8*)(Wh + wrow);
            bl[nf] = *(const bf16x8*)(Wl + wrow);
        }
#pragma unroll
        for (int mf = 0; mf < 3; mf++)
#pragma unroll
            for (int nf = 0; nf < NF; nf++) {
                acc[mf][nf] = __builtin_amdgcn_mfma_f32_16x16x32_bf16(ah[mf], bh[nf], acc[mf][nf], 0, 0, 0);
                acc[mf][nf] = __builtin_amdgcn_mfma_f32_16x16x32_bf16(ah[mf], bl[nf], acc[mf][nf], 0, 0, 0);
                acc[mf][nf] = __builtin_amdgcn_mfma_f32_16x16x32_bf16(al[mf], bh[nf], acc[mf][nf], 0, 0, 0);
            }
    }

    // stage PD tile: row = mf*16 + q*4 + i, col = wv*16*NF + nf*16 + mr
#pragma unroll
    for (int mf = 0; mf < 3; mf++)
#pragma unroll
        for (int nf = 0; nf < NF; nf++)
#pragma unroll
            for (int i = 0; i < 4; i++)
                tb[(size_t)(mf * 16 + q * 4 + i) * LDT + wv * 16 * NF + nf * 16 + mr] = acc[mf][nf][i];
    __syncthreads();

    const int bp0 = blockIdx.x * 16;   // first point of this block
#pragma unroll
    for (int it = 0; it < 8; it++) {
        const int item = it * 256 + tid;   // 2048 = 16 pts x 128 o
        const int o = item & 127;
        const int pt = item >> 7;
        float p[3], d[3];
#pragma unroll
        for (int v = 0; v < 3; v++) {
            const int r = pt * 3 + v;
            p[v] = tb[(size_t)r * LDT + o];
            d[v] = WCMODE ? tb[(size_t)r * LDT + 128] : tb[(size_t)r * LDT + 128 + o];
        }
        float dot = fmaf(p[2], d[2], fmaf(p[1], d[1], p[0] * d[0]));
        float dsq = fmaf(d[2], d[2], fmaf(d[1], d[1], d[0] * d[0]));
        float s = (dot < 0.f) ? 0.8f * dot / (dsq + 1e-6f) : 0.f;
#pragma unroll
        for (int v = 0; v < 3; v++) {
            unsigned short h, l;
            split_bf16(fmaf(-s, d[v], p[v]), h, l);
            const size_t ob = ((size_t)(bp0 + pt) * 3 + v) * 128 + o;
            oh[ob] = h; ol[ob] = l;
        }
    }
}

// ---------------------------------------------------------------------------
// Edge conv + vec_lna + mean over K neighbors -> bf16 hi/lo output (ld 256).
// fp16 AH gather (interleaved AF AD pairs); fp32 AG center terms; XCD swizzle.
// ---------------------------------------------------------------------------
template <int O, int PT>
__global__ __launch_bounds__(256, 6) void edge_kernel(const __half* __restrict__ AH,
                                                      const float* __restrict__ AG,
                                                      const int* __restrict__ idx,
                                                      unsigned short* __restrict__ outh,
                                                      unsigned short* __restrict__ outl,
                                                      int ooff)
{
    constexpr int TP = O / 2;          // threads per point
    constexpr int twoO = 2 * O;
    const int lb = xcd_swizzle(blockIdx.x, gridDim.x);
    const int tid = threadIdx.x;
    const int op = tid % TP;
    const int pt = tid / TP;
    const int gp = lb * PT + pt;
    const int b = gp >> 11;
    __shared__ int sIdx[PT][KNN_K];
    for (int j = tid; j < PT * KNN_K; j += 256)
        sIdx[j >> 4][j & 15] = idx[(lb * PT + (j >> 4)) * KNN_K + (j & 15)];
    __syncthreads();
    const int rown = gp * 3;
    const float4 c0 = *(const float4*)&AG[(size_t)(rown + 0) * twoO + 4 * op];
    const float4 c1 = *(const float4*)&AG[(size_t)(rown + 1) * twoO + 4 * op];
    const float4 c2 = *(const float4*)&AG[(size_t)(rown + 2) * twoO + 4 * op];
    float ax0 = 0.f, ax1 = 0.f, ax2 = 0.f;   // o = 2op
    float ay0 = 0.f, ay1 = 0.f, ay2 = 0.f;   // o = 2op+1
    const int bbase = (b << 11) * 3;
#pragma unroll 2
    for (int k = 0; k < KNN_K; k++) {
        int m = sIdx[pt][k];
        const __half* base = AH + (size_t)(bbase + m * 3) * twoO + 4 * op;
        uint2 u0 = *(const uint2*)(base);
        uint2 u1 = *(const uint2*)(base + twoO);
        uint2 u2 = *(const uint2*)(base + 2 * twoO);
        float2 e0 = __half22float2(*(__half2*)&u0.x);
        float2 f0 = __half22float2(*(__half2*)&u0.y);
        float2 e1 = __half22float2(*(__half2*)&u1.x);
        float2 f1 = __half22float2(*(__half2*)&u1.y);
        float2 e2 = __half22float2(*(__half2*)&u2.x);
        float2 f2 = __half22float2(*(__half2*)&u2.y);
        {
            float p0 = e0.x + c0.x, d0 = e0.y + c0.y;
            float p1 = e1.x + c1.x, d1 = e1.y + c1.y;
            float p2 = e2.x + c2.x, d2 = e2.y + c2.y;
            float dot = fmaf(p2, d2, fmaf(p1, d1, p0 * d0));
            float dsq = fmaf(d2, d2, fmaf(d1, d1, d0 * d0));
            float s = (dot < 0.f) ? 0.8f * dot / (dsq + 1e-6f) : 0.f;
            ax0 += fmaf(-s, d0, p0);
            ax1 += fmaf(-s, d1, p1);
            ax2 += fmaf(-s, d2, p2);
        }
        {
            float p0 = f0.x + c0.z, d0 = f0.y + c0.w;
            float p1 = f1.x + c1.z, d1 = f1.y + c1.w;
            float p2 = f2.x + c2.z, d2 = f2.y + c2.w;
            float dot = fmaf(p2, d2, fmaf(p1, d1, p0 * d0));
            float dsq = fmaf(d2, d2, fmaf(d1, d1, d0 * d0));
            float s = (dot < 0.f) ? 0.8f * dot / (dsq + 1e-6f) : 0.f;
            ay0 += fmaf(-s, d0, p0);
            ay1 += fmaf(-s, d1, p1);
            ay2 += fmaf(-s, d2, p2);
        }
    }
    float rx[3] = { ax0 * 0.0625f, ax1 * 0.0625f, ax2 * 0.0625f };
    float ry[3] = { ay0 * 0.0625f, ay1 * 0.0625f, ay2 * 0.0625f };
#pragma unroll
    for (int v = 0; v < 3; v++) {
        unsigned short hx, lx, hy, ly;
        split_bf16(rx[v], hx, lx);
        split_bf16(ry[v], hy, ly);
        const size_t ob = (size_t)(rown + v) * 256 + ooff + 2 * op;
        *(unsigned*)(outh + ob) = (unsigned)hx | ((unsigned)hy << 16);
        *(unsigned*)(outl + ob) = (unsigned)lx | ((unsigned)ly << 16);
    }
}

// ---------------------------------------------------------------------------
// xm: partial sums over n of xc2 (ld 128), then mean -> 12x128 bf16-pair table
// ---------------------------------------------------------------------------
__global__ void xm_partial_kernel(const unsigned short* __restrict__ xh,
                                  const unsigned short* __restrict__ xl,
                                  float* __restrict__ part)
{
    const int g = blockIdx.x;        // B*3*32 = 384
    const int s = g & 31;
    const int bv = g >> 5;           // 0..11  (b*3+v)
    const int b = bv / 3;
    const int v = bv % 3;
    const int o = threadIdx.x;       // 128
    float acc = 0.f;
    for (int i = 0; i < 64; i++) {
        int n = s * 64 + i;
        size_t ix = (size_t)((b * NPTS + n) * 3 + v) * 128 + o;
        acc += bf2(xh[ix], xl[ix]);
    }
    part[(bv * 32 + s) * 128 + o] = acc;
}

__global__ void xm_final_kernel(const float* __restrict__ part,
                                unsigned short* __restrict__ xmh,
                                unsigned short* __restrict__ xml)
{
    const int bv = blockIdx.x;       // 12
    const int o = threadIdx.x;       // 128
    float acc = 0.f;
    for (int i = 0; i < 32; i++) acc += part[(bv * 32 + i) * 128 + o];
    unsigned short h, l;
    split_bf16(acc * (1.f / 2048.f), h, l);
    xmh[bv * 128 + o] = h;
    xml[bv * 128 + o] = l;
}

// ---------------------------------------------------------------------------
// final: vec_lna(wi2 PD) fused with inv = sum_v xcat2 * x0, LDS transpose.
// xcat2 col o<128 from xc2 (ld 128); o>=128 from the 12x128 xm table.
// ---------------------------------------------------------------------------
__global__ __launch_bounds__(256) void final_inv_kernel(const float* __restrict__ PD2,
                                                        const unsigned short* __restrict__ xch,
                                                        const unsigned short* __restrict__ xcl,
                                                        const unsigned short* __restrict__ xmh,
                                                        const unsigned short* __restrict__ xml,
                                                        float* __restrict__ out)
{
    __shared__ float sh[32][257];
    const int tid = threadIdx.x;     // o = tid, 0..255
    const int base_gp = blockIdx.x * 32;
    const int b = base_gp >> 11;
    const int n0 = base_gp & (NPTS - 1);
    for (int pt = 0; pt < 32; pt++) {
        const int row = (base_gp + pt) * 3;
        float p[3], d[3], xc[3];
#pragma unroll
        for (int v = 0; v < 3; v++) {
            p[v]  = PD2[(size_t)(row + v) * 512 + tid];
            d[v]  = PD2[(size_t)(row + v) * 512 + 256 + tid];
            if (tid < 128) {
                size_t ix = (size_t)(row + v) * 128 + tid;
                xc[v] = bf2(xch[ix], xcl[ix]);
            } else {
                size_t ix = (size_t)(b * 3 + v) * 128 + tid - 128;
                xc[v] = bf2(xmh[ix], xml[ix]);
            }
        }
        float dot = fmaf(p[2], d[2], fmaf(p[1], d[1], p[0] * d[0]));
        float dsq = fmaf(d[2], d[2], fmaf(d[1], d[1], d[0] * d[0]));
        float s = (dot < 0.f) ? 0.8f * dot / (dsq + 1e-6f) : 0.f;
        float inv = 0.f;
#pragma unroll
        for (int v = 0; v < 3; v++) {
            inv = fmaf(xc[v], fmaf(-s, d[v], p[v]), inv);
        }
        sh[pt][tid] = inv;
    }
    __syncthreads();
#pragma unroll
    for (int j = 0; j < 32; j++) {
        int ow = (tid >> 5) + j * 8;
        int pt2 = tid & 31;
        out[((size_t)b * 256 + ow) * NPTS + n0 + pt2] = sh[pt2][ow];
    }
}

// ---------------------------------------------------------------------------
// launch
// ---------------------------------------------------------------------------
extern "C" void kernel_launch(void* const* d_in, const int* in_sizes, int n_in,
                              void* d_out, int out_size, void* d_ws, size_t ws_size,
                              hipStream_t stream)
{
    const float* x    = (const float*)d_in[0];
    const float* w1f  = (const float*)d_in[1];
    const float* w1d  = (const float*)d_in[2];
    const float* w2f  = (const float*)d_in[3];
    const float* w2d  = (const float*)d_in[4];
    const float* w3f  = (const float*)d_in[5];
    const float* w3d  = (const float*)d_in[6];
    const float* w4f  = (const float*)d_in[7];
    const float* w4d  = (const float*)d_in[8];
    const float* wcf  = (const float*)d_in[9];
    const float* wcd  = (const float*)d_in[10];
    const float* wi1f = (const float*)d_in[11];
    const float* wi1d = (const float*)d_in[12];
    const float* wi2f = (const float*)d_in[13];
    const float* wi2d = (const float*)d_in[14];
    float* out = (float*)d_out;

    float* F = (float*)d_ws;
    size_t off = 0;
    float* AG = F + off;                          off += (size_t)MROWS * 512;  // fp32 PD / G-half buffer
    __half* AH = (__half*)(F + off);              off += (size_t)MROWS * 128;  // fp16 A-half
    unsigned short* X240h = (unsigned short*)(F + off); off += (size_t)MROWS * 128;
    unsigned short* X240l = (unsigned short*)(F + off); off += (size_t)MROWS * 128;
    unsigned short* xc2h  = (unsigned short*)(F + off); off += (size_t)MROWS * 64;  // ld 128 now
    unsigned short* xc2l  = (unsigned short*)(F + off); off += (size_t)MROWS * 64;
    unsigned short* Wb2h = (unsigned short*)(F + off); off += 2048;
    unsigned short* Wb2l = (unsigned short*)(F + off); off += 2048;
    unsigned short* Wb3h = (unsigned short*)(F + off); off += 4096;
    unsigned short* Wb3l = (unsigned short*)(F + off); off += 4096;
    unsigned short* Wb4h = (unsigned short*)(F + off); off += 16384;
    unsigned short* Wb4l = (unsigned short*)(F + off); off += 16384;
    unsigned short* Wch  = (unsigned short*)(F + off); off += 24576;
    unsigned short* Wcl  = (unsigned short*)(F + off); off += 24576;
    unsigned short* Wi1h = (unsigned short*)(F + off); off += 32768;
    unsigned short* Wi1l = (unsigned short*)(F + off); off += 32768;
    unsigned short* Wi2h = (unsigned short*)(F + off); off += 32768;
    unsigned short* Wi2l = (unsigned short*)(F + off); off += 32768;
    float* part = F + off;                        off += 12 * 32 * 128;
    unsigned short* xmph = (unsigned short*)(F + off); off += 768;   // 12*128 u16
    unsigned short* xmpl = (unsigned short*)(F + off); off += 768;
    int* idx    = (int*)(F + off);                off += NBP * KNN_K;
    unsigned short* y1h = X240h;   // alias: X240 dead after wc GEMM
    unsigned short* y1l = X240l;

    // prep (layer-1 from x + all weight builds) + knn
    prep_kernel<<<(PC6 + 255) / 256, 256, 0, stream>>>(
        x, AH, AG, w1f, w1d,
        w2f, w2d, Wb2h, Wb2l, w3f, w3d, Wb3h, Wb3l, w4f, w4d, Wb4h, Wb4l,
        wcf, wcd, Wch, Wcl, wi1f, wi1d, Wi1h, Wi1l, wi2f, wi2d, Wi2h, Wi2l);
    knn_kernel<<<NBP, 64, 0, stream>>>(x, idx);

    const int GM = MROWS / 256;   // 96

    // layer 1 edge (AH/AG filled by prep)
    edge_kernel<16, 32><<<NBP / 32, 256, 0, stream>>>(AH, AG, idx, X240h, X240l, 0);
    // layer 2: K=16 (pad 32), O=32
    gemm_mfma<<<dim3(GM, 2), 256, 0, stream>>>(X240h, X240l, 256, 0, Wb2h, Wb2l, nullptr, 0, 128, 32, AH, AG, 64);
    edge_kernel<32, 16><<<NBP / 16, 256, 0, stream>>>(AH, AG, idx, X240h, X240l, 16);
    // layer 3: K=32, O=64
    gemm_mfma<<<dim3(GM, 4), 256, 0, stream>>>(X240h, X240l, 256, 16, Wb3h, Wb3l, nullptr, 0, 256, 32, AH, AG, 128);
    edge_kernel<64, 8><<<NBP / 8, 256, 0, stream>>>(AH, AG, idx, X240h, X240l, 48);
    // layer 4: K=64, O=128
    gemm_mfma<<<dim3(GM, 8), 256, 0, stream>>>(X240h, X240l, 256, 48, Wb4h, Wb4l, nullptr, 0, 512, 64, AH, AG, 256);
    edge_kernel<128, 4><<<NBP / 4, 256, 0, stream>>>(AH, AG, idx, X240h, X240l, 112);

    // wc (K=240 pad 256) fused with vec_lna -> xc2 pair (ld 128)
    gemm_lna<3, true><<<MROWS / 48, 256, 0, stream>>>(X240h, X240l, 256, nullptr, nullptr,
                                                      Wch, Wcl, 256, xc2h, xc2l);

    // xm mean -> 12x128 bf16-pair table
    xm_partial_kernel<<<BATCH * 3 * 32, 128, 0, stream>>>(xc2h, xc2l, part);
    xm_final_kernel<<<BATCH * 3, 128, 0, stream>>>(part, xmph, xmpl);

    // wi1 (K=256: k<128 from xc2, k>=128 from xm table) fused with vec_lna -> y1
    gemm_lna<4, false><<<MROWS / 48, 256, 0, stream>>>(xc2h, xc2l, 128, xmph, xmpl,
                                                       Wi1h, Wi1l, 256, y1h, y1l);

    // wi2: K=128 -> PD [MROWS,512] -> fused lna + inv + transpose
    gemm_mfma<<<dim3(GM, 8), 256, 0, stream>>>(y1h, y1l, 128, 0, Wi2h, Wi2l, AG, 512, 512, 128, nullptr, nullptr, 0);
    final_inv_kernel<<<NBP / 32, 256, 0, stream>>>(AG, xc2h, xc2l, xmph, xmpl, out);

    (void)in_sizes; (void)n_in; (void)out_size; (void)ws_size;
}

// Round 12
// 324.704 us; speedup vs baseline: 1.0397x; 1.0397x over previous
//
#include <hip/hip_runtime.h>
#include <hip/hip_fp16.h>

#define NPTS  2048
#define BATCH 4
#define NBP   8192      // BATCH*NPTS
#define MROWS 24576     // NBP*3
#define KNN_K 16

typedef short bf16x8 __attribute__((ext_vector_type(8)));
typedef float f32x4  __attribute__((ext_vector_type(4)));

// split fp32 into bf16 hi + bf16 lo (RTNE), x ~= hi + lo to ~2^-17 rel
static __device__ __forceinline__ void split_bf16(float a, unsigned short& h, unsigned short& l)
{
    unsigned u = __float_as_uint(a);
    unsigned hr = (u + 0x7FFFu + ((u >> 16) & 1u)) & 0xFFFF0000u;
    h = (unsigned short)(hr >> 16);
    float rem = a - __uint_as_float(hr);
    unsigned v = __float_as_uint(rem);
    l = (unsigned short)((v + 0x7FFFu + ((v >> 16) & 1u)) >> 16);
}

static __device__ __forceinline__ float bf2(unsigned short h, unsigned short l)
{
    return __uint_as_float((unsigned)h << 16) + __uint_as_float((unsigned)l << 16);
}

static __device__ __forceinline__ unsigned long long shfl_xor_u64(unsigned long long v, int mask)
{
    unsigned lo = (unsigned)v, hi = (unsigned)(v >> 32);
    lo = (unsigned)__shfl_xor((int)lo, mask, 64);
    hi = (unsigned)__shfl_xor((int)hi, mask, 64);
    return ((unsigned long long)hi << 32) | lo;
}

// XCD-confinement swizzle (bijection; wrong mapping assumption = speed-neutral)
static __device__ __forceinline__ int xcd_swizzle(int i, int G)
{
    int batch  = (i >> 1) & 3;
    int within = ((i >> 3) << 1) | (i & 1);
    return batch * (G >> 2) + within;
}

// interleaved edge-weight element: rows j<2O: AF0 AD0 AF1 AD1...; j>=2O: GF0 GD0...
static __device__ __forceinline__ float wbig_val(const float* __restrict__ Wf,
                                                 const float* __restrict__ Wd,
                                                 int j, int c, int O, int C)
{
    if (j < 2 * O) {
        int o = j >> 1;
        return (j & 1) ? Wd[o * 2 * C + c] : Wf[o * 2 * C + c];
    }
    int o = (j - 2 * O) >> 1;
    return (j & 1) ? (Wd[o * 2 * C + C + c] - Wd[o * 2 * C + c])
                   : (Wf[o * 2 * C + C + c] - Wf[o * 2 * C + c]);
}

// ---------------------------------------------------------------------------
// prep mega-kernel: layer-1 (K=1 GEMM straight from x) + all weight builds
// ---------------------------------------------------------------------------
#define PC0 1572864          // l1: MROWS*64 -> AH/AG
#define PC1 (PC0 + 4096)     // Wb2 (O=32,C=16,Kp=32)
#define PC2 (PC1 + 8192)     // Wb3 (O=64,C=32,Kp=32)
#define PC3 (PC2 + 32768)    // Wb4 (O=128,C=64,Kp=64)
#define PC4 (PC3 + 49152)    // Wc stack (192 x 256)
#define PC5 (PC4 + 65536)    // Wi1 stack (256 x 256)
#define PC6 (PC5 + 65536)    // Wi2 stack (512 x 128)

__global__ __launch_bounds__(256) void prep_kernel(
    const float* __restrict__ x, __half* __restrict__ AH, float* __restrict__ AG,
    const float* __restrict__ w1f, const float* __restrict__ w1d,
    const float* __restrict__ w2f, const float* __restrict__ w2d,
    unsigned short* __restrict__ Wb2h, unsigned short* __restrict__ Wb2l,
    const float* __restrict__ w3f, const float* __restrict__ w3d,
    unsigned short* __restrict__ Wb3h, unsigned short* __restrict__ Wb3l,
    const float* __restrict__ w4f, const float* __restrict__ w4d,
    unsigned short* __restrict__ Wb4h, unsigned short* __restrict__ Wb4l,
    const float* __restrict__ wcf, const float* __restrict__ wcd,
    unsigned short* __restrict__ Wch, unsigned short* __restrict__ Wcl,
    const float* __restrict__ wi1f, const float* __restrict__ wi1d,
    unsigned short* __restrict__ Wi1h, unsigned short* __restrict__ Wi1l,
    const float* __restrict__ wi2f, const float* __restrict__ wi2d,
    unsigned short* __restrict__ Wi2h, unsigned short* __restrict__ Wi2l)
{
    int i = blockIdx.x * 256 + threadIdx.x;
    if (i < PC0) {
        // layer-1: out[row, o] = x_row * Wb1[o]  (interleaved A|G split)
        int o = i & 63;
        int row = i >> 6;
        int v = row % 3;
        int gp = row / 3;
        int b = gp >> 11;
        int n = gp & (NPTS - 1);
        float xv = x[(b * 3 + v) * NPTS + n];
        float wv = wbig_val(w1f, w1d, o, 0, 16, 1);
        float val = xv * wv;
        if (o < 32) AH[(size_t)row * 32 + o] = __float2half(val);
        else        AG[(size_t)row * 32 + o - 32] = val;
    } else if (i < PC6) {
        float v = 0.f;
        unsigned short *ph, *pl;
        int ix;
        if (i < PC1) {            // Wb2: O=32,C=16,Kpad=32
            ix = i - PC0;
            int c = ix & 31, j = ix >> 5;
            if (c < 16) v = wbig_val(w2f, w2d, j, c, 32, 16);
            ph = Wb2h; pl = Wb2l;
        } else if (i < PC2) {     // Wb3: O=64,C=32,Kpad=32
            ix = i - PC1;
            int c = ix & 31, j = ix >> 5;
            v = wbig_val(w3f, w3d, j, c, 64, 32);
            ph = Wb3h; pl = Wb3l;
        } else if (i < PC3) {     // Wb4: O=128,C=64,Kpad=64
            ix = i - PC2;
            int c = ix & 63, j = ix >> 6;
            v = wbig_val(w4f, w4d, j, c, 128, 64);
            ph = Wb4h; pl = Wb4l;
        } else if (i < PC4) {     // Wc: stack wcf(128) + wcd(1), K=240, 192x256
            ix = i - PC3;
            int c = ix & 255, r = ix >> 8;
            if (c < 240) {
                if (r < 128) v = wcf[r * 240 + c];
                else if (r < 129) v = wcd[(r - 128) * 240 + c];
            }
            ph = Wch; pl = Wcl;
        } else if (i < PC5) {     // Wi1: stack wi1f(128)+wi1d(128), K=256, 256x256
            ix = i - PC4;
            int c = ix & 255, r = ix >> 8;
            if (r < 128) v = wi1f[r * 256 + c];
            else v = wi1d[(r - 128) * 256 + c];
            ph = Wi1h; pl = Wi1l;
        } else {                  // Wi2: stack wi2f(256)+wi2d(256), K=128, 512x128
            ix = i - PC5;
            int c = ix & 127, r = ix >> 7;
            if (r < 256) v = wi2f[r * 128 + c];
            else v = wi2d[(r - 256) * 128 + c];
            ph = Wi2h; pl = Wi2l;
        }
        unsigned short h, l;
        split_bf16(v, h, l);
        ph[ix] = h; pl[ix] = l;
    }
}

// ---------------------------------------------------------------------------
// KNN v4: one 64-thread block (= one wave) per query; keys in LDS; incremental
// argmin; ONE u64 butterfly per round packing (key<<32)|(slot<<6)|lane so
// min == lexicographic (d2, m) == top_k order.
// ---------------------------------------------------------------------------
__global__ __launch_bounds__(64) void knn_kernel(const float* __restrict__ x, int* __restrict__ idx)
{
    __shared__ unsigned ksh[64 * 34];
    const int t  = threadIdx.x;       // 0..63
    const int bn = blockIdx.x;        // query id
    const int b = bn >> 11;
    const int n = bn & (NPTS - 1);
    const float* xb = x + b * 3 * NPTS;
    const float qx = xb[n], qy = xb[NPTS + n], qz = xb[2 * NPTS + n];
    const float sqn = fmaf(qz, qz, fmaf(qy, qy, qx * qx));
    unsigned* ks = &ksh[t * 34];

    unsigned gm[4];
    int ga[4];
#pragma unroll
    for (int g = 0; g < 4; g++) {
        unsigned kk[8];
#pragma unroll
        for (int j = 0; j < 8; j++) {
            const int i = g * 8 + j;
            const int m = (i << 6) + t;
            float mx = xb[m], my = xb[NPTS + m], mz = xb[2 * NPTS + m];
            float sqm = fmaf(mz, mz, fmaf(my, my, mx * mx));
            float dt  = fmaf(qz, mz, fmaf(qy, my, qx * mx));
            float d2  = sqn + sqm - 2.0f * dt;
            unsigned u = __float_as_uint(d2);
            u ^= (u & 0x80000000u) ? 0xFFFFFFFFu : 0x80000000u;  // monotone map
            kk[j] = u;
        }
        *(uint2*)&ks[g * 8 + 0] = make_uint2(kk[0], kk[1]);
        *(uint2*)&ks[g * 8 + 2] = make_uint2(kk[2], kk[3]);
        *(uint2*)&ks[g * 8 + 4] = make_uint2(kk[4], kk[5]);
        *(uint2*)&ks[g * 8 + 6] = make_uint2(kk[6], kk[7]);
        unsigned bg = kk[0];
        int ba = g * 8;
#pragma unroll
        for (int j = 1; j < 8; j++) {       // ascending + strict < keeps lowest slot on tie
            if (kk[j] < bg) { bg = kk[j]; ba = g * 8 + j; }
        }
        gm[g] = bg; ga[g] = ba;
    }
    unsigned lm = gm[0];
    int il = ga[0];
#pragma unroll
    for (int g = 1; g < 4; g++) if (gm[g] < lm) { lm = gm[g]; il = ga[g]; }

    unsigned long long pk = ((unsigned long long)lm << 32) | (unsigned)((il << 6) | t);
    int res = -1;
    for (int r = 0; r < KNN_K; r++) {
        unsigned long long w = pk;
#pragma unroll
        for (int off = 32; off > 0; off >>= 1) {
            unsigned long long o = shfl_xor_u64(w, off);
            w = (o < w) ? o : w;
        }
        if (t == r) res = (int)(w & 0xFFFFFFFFull);

        if (pk == w) {                    // exactly one owner lane (m unique)
            ks[il] = 0xFFFFFFFFu;         // zap (computed LDS address)
            const int g = il >> 3;
            unsigned bg = ks[g * 8];
            int ba = g * 8;
#pragma unroll
            for (int j = 1; j < 8; j++) {
                unsigned kv = ks[g * 8 + j];
                if (kv < bg) { bg = kv; ba = g * 8 + j; }
            }
            gm[g] = bg; ga[g] = ba;
            lm = gm[0]; il = ga[0];
#pragma unroll
            for (int g2 = 1; g2 < 4; g2++) if (gm[g2] < lm) { lm = gm[g2]; il = ga[g2]; }
            pk = ((unsigned long long)lm << 32) | (unsigned)((il << 6) | t);
        }
    }
    if (t < KNN_K) idx[bn * KNN_K + t] = res;
}

// ---------------------------------------------------------------------------
// Split-bf16 MFMA GEMM (NT): R10's LDS-staged W K-loop restored (R11 lesson:
// global B-frag loads inside the MFMA chain cost more than the 2 barriers).
// Epilogue modes:
//  - OUTA==null: fp32 OUT [m, ldo]
//  - OUTA!=null (edge): col<twoO -> fp16 OUTA [m, twoO]; else fp32 OUTG
// ---------------------------------------------------------------------------
__global__ __launch_bounds__(256) void gemm_mfma(
    const unsigned short* __restrict__ Xh, const unsigned short* __restrict__ Xl,
    int ldx, int xoff,
    const unsigned short* __restrict__ Wh, const unsigned short* __restrict__ Wl,
    float* __restrict__ OUT, int ldo, int Nout, int Kpad,
    __half* __restrict__ OUTA, float* __restrict__ OUTG, int twoO)
{
    __shared__ unsigned short Ws[2][64][56];
    const int tid = threadIdx.x;
    const int bm = blockIdx.x * 256;
    const int bo = blockIdx.y * 64;
    const int lane = tid & 63;
    const int wv = tid >> 6;
    const int mr = lane & 15;
    const int q  = lane >> 4;

    f32x4 acc[4][4];
#pragma unroll
    for (int a = 0; a < 4; a++)
#pragma unroll
        for (int c = 0; c < 4; c++) acc[a][c] = (f32x4){0.f, 0.f, 0.f, 0.f};

    const int wr = tid >> 2;   // 0..63
    const int sc = tid & 3;    // k-chunk 0..3

    for (int k0 = 0; k0 < Kpad; k0 += 32) {
        {
            const uint4 vh = *(const uint4*)(Wh + (size_t)(bo + wr) * Kpad + k0 + sc * 8);
            const uint4 vl = *(const uint4*)(Wl + (size_t)(bo + wr) * Kpad + k0 + sc * 8);
            *(uint4*)&Ws[0][wr][sc * 8] = vh;
            *(uint4*)&Ws[1][wr][sc * 8] = vl;
        }
        __syncthreads();

        bf16x8 ah[4], al[4], bh[4], bl[4];
#pragma unroll
        for (int mf = 0; mf < 4; mf++) {
            const size_t xrow = (size_t)(bm + wv * 64 + mf * 16 + mr) * ldx + xoff + k0 + q * 8;
            ah[mf] = *(const bf16x8*)(Xh + xrow);
            al[mf] = *(const bf16x8*)(Xl + xrow);
        }
#pragma unroll
        for (int nf = 0; nf < 4; nf++) {
            bh[nf] = *(const bf16x8*)&Ws[0][nf * 16 + mr][q * 8];
            bl[nf] = *(const bf16x8*)&Ws[1][nf * 16 + mr][q * 8];
        }
#pragma unroll
        for (int mf = 0; mf < 4; mf++)
#pragma unroll
            for (int nf = 0; nf < 4; nf++) {
                acc[mf][nf] = __builtin_amdgcn_mfma_f32_16x16x32_bf16(ah[mf], bh[nf], acc[mf][nf], 0, 0, 0);
                acc[mf][nf] = __builtin_amdgcn_mfma_f32_16x16x32_bf16(ah[mf], bl[nf], acc[mf][nf], 0, 0, 0);
                acc[mf][nf] = __builtin_amdgcn_mfma_f32_16x16x32_bf16(al[mf], bh[nf], acc[mf][nf], 0, 0, 0);
            }
        __syncthreads();
    }

    // epilogue: D layout col=lane&15, row=q*4+i
    if (OUTA) {
#pragma unroll
        for (int nf = 0; nf < 4; nf++) {
            const int col = bo + nf * 16 + mr;
            if (col < twoO) {
#pragma unroll
                for (int mf = 0; mf < 4; mf++)
#pragma unroll
                    for (int i = 0; i < 4; i++) {
                        const int row = bm + wv * 64 + mf * 16 + q * 4 + i;
                        OUTA[(size_t)row * twoO + col] = __float2half(acc[mf][nf][i]);
                    }
            } else {
#pragma unroll
                for (int mf = 0; mf < 4; mf++)
#pragma unroll
                    for (int i = 0; i < 4; i++) {
                        const int row = bm + wv * 64 + mf * 16 + q * 4 + i;
                        OUTG[(size_t)row * twoO + col - twoO] = acc[mf][nf][i];
                    }
            }
        }
    } else {
#pragma unroll
        for (int nf = 0; nf < 4; nf++) {
            const int col = bo + nf * 16 + mr;
            if (col < Nout) {
#pragma unroll
                for (int mf = 0; mf < 4; mf++)
#pragma unroll
                    for (int i = 0; i < 4; i++) {
                        const int row = bm + wv * 64 + mf * 16 + q * 4 + i;
                        OUT[(size_t)row * ldo + col] = acc[mf][nf][i];
                    }
            }
        }
    }
}

// ---------------------------------------------------------------------------
// Fused GEMM + vec_lna (wc / wi1), R10's LDS W-staging restored. Block:
// 4 waves, M-tile 48 rows (16 points), N = full width (4 x NF x 16 = NC).
// If xmh != null, A-frags for k>=128 come from the 12x128 xm table; else Xh/Xl
// at ld ldx. After the K-loop the 48 x NC fp32 PD tile goes to LDS (union with
// the W stage), lna computes in-block, writes bf16-pair outputs at ld 128.
// WCMODE: d = col 128 (shared); else d = cols 128..255. Bit-identical math.
// ---------------------------------------------------------------------------
template <int NF, bool WCMODE>
__global__ __launch_bounds__(256, 3) void gemm_lna(
    const unsigned short* __restrict__ Xh, const unsigned short* __restrict__ Xl, int ldx,
    const unsigned short* __restrict__ xmh, const unsigned short* __restrict__ xml,
    const unsigned short* __restrict__ Wh, const unsigned short* __restrict__ Wl,
    int Kpad,
    unsigned short* __restrict__ oh, unsigned short* __restrict__ ol)
{
    constexpr int NC  = NF * 64;       // total output cols
    constexpr int LDW = 40;            // u16 stride (80B, 16B-aligned rows)
    constexpr int LDT = NC + 1;        // fp32 tile stride
    constexpr int WB  = 2 * NC * LDW * 2;
    constexpr int TB  = 48 * LDT * 4;
    constexpr int SB  = (WB > TB) ? WB : TB;
    __shared__ __align__(16) char smem[SB];
    unsigned short* wb = (unsigned short*)smem;
    float* tb = (float*)smem;

    const int tid = threadIdx.x;
    const int bm = blockIdx.x * 48;
    const int lane = tid & 63;
    const int wv = tid >> 6;
    const int mr = lane & 15;
    const int q  = lane >> 4;

    f32x4 acc[3][NF];
#pragma unroll
    for (int a = 0; a < 3; a++)
#pragma unroll
        for (int c = 0; c < NF; c++) acc[a][c] = (f32x4){0.f, 0.f, 0.f, 0.f};

    for (int k0 = 0; k0 < Kpad; k0 += 32) {
        for (int rr = tid; rr < NC; rr += 256) {
#pragma unroll
            for (int sc = 0; sc < 4; sc++) {
                *(uint4*)&wb[(size_t)rr * LDW + sc * 8] =
                    *(const uint4*)(Wh + (size_t)rr * Kpad + k0 + sc * 8);
                *(uint4*)&wb[(size_t)(NC + rr) * LDW + sc * 8] =
                    *(const uint4*)(Wl + (size_t)rr * Kpad + k0 + sc * 8);
            }
        }
        __syncthreads();

        bf16x8 ah[3], al[3], bh[NF], bl[NF];
#pragma unroll
        for (int mf = 0; mf < 3; mf++) {
            const int row = bm + mf * 16 + mr;
            size_t xrow;
            const unsigned short *sh_, *sl_;
            if (xmh != nullptr && k0 >= 128) {
                const int gp = row / 3;
                const int v = row - gp * 3;
                const int b = gp >> 11;
                xrow = (size_t)(b * 3 + v) * 128 + (k0 - 128) + q * 8;
                sh_ = xmh; sl_ = xml;
            } else {
                xrow = (size_t)row * ldx + k0 + q * 8;
                sh_ = Xh; sl_ = Xl;
            }
            ah[mf] = *(const bf16x8*)(sh_ + xrow);
            al[mf] = *(const bf16x8*)(sl_ + xrow);
        }
#pragma unroll
        for (int nf = 0; nf < NF; nf++) {
            const int wr = wv * 16 * NF + nf * 16 + mr;
            bh[nf] = *(const bf16x8*)&wb[(size_t)wr * LDW + q * 8];
            bl[nf] = *(const bf16x8*)&wb[(size_t)(NC + wr) * LDW + q * 8];
        }
#pragma unroll
        for (int mf = 0; mf < 3; mf++)
#pragma unroll
            for (int nf = 0; nf < NF; nf++) {
                acc[mf][nf] = __builtin_amdgcn_mfma_f32_16x16x32_bf16(ah[mf], bh[nf], acc[mf][nf], 0, 0, 0);
                acc[mf][nf] = __builtin_amdgcn_mfma_f32_16x16x32_bf16(ah[mf], bl[nf], acc[mf][nf], 0, 0, 0);
                acc[mf][nf] = __builtin_amdgcn_mfma_f32_16x16x32_bf16(al[mf], bh[nf], acc[mf][nf], 0, 0, 0);
            }
        __syncthreads();   // also protects wb before tile reuse
    }

    // stage PD tile: row = mf*16 + q*4 + i, col = wv*16*NF + nf*16 + mr
#pragma unroll
    for (int mf = 0; mf < 3; mf++)
#pragma unroll
        for (int nf = 0; nf < NF; nf++)
#pragma unroll
            for (int i = 0; i < 4; i++)
                tb[(size_t)(mf * 16 + q * 4 + i) * LDT + wv * 16 * NF + nf * 16 + mr] = acc[mf][nf][i];
    __syncthreads();

    const int bp0 = blockIdx.x * 16;   // first point of this block
#pragma unroll
    for (int it = 0; it < 8; it++) {
        const int item = it * 256 + tid;   // 2048 = 16 pts x 128 o
        const int o = item & 127;
        const int pt = item >> 7;
        float p[3], d[3];
#pragma unroll
        for (int v = 0; v < 3; v++) {
            const int r = pt * 3 + v;
            p[v] = tb[(size_t)r * LDT + o];
            d[v] = WCMODE ? tb[(size_t)r * LDT + 128] : tb[(size_t)r * LDT + 128 + o];
        }
        float dot = fmaf(p[2], d[2], fmaf(p[1], d[1], p[0] * d[0]));
        float dsq = fmaf(d[2], d[2], fmaf(d[1], d[1], d[0] * d[0]));
        float s = (dot < 0.f) ? 0.8f * dot / (dsq + 1e-6f) : 0.f;
#pragma unroll
        for (int v = 0; v < 3; v++) {
            unsigned short h, l;
            split_bf16(fmaf(-s, d[v], p[v]), h, l);
            const size_t ob = ((size_t)(bp0 + pt) * 3 + v) * 128 + o;
            oh[ob] = h; ol[ob] = l;
        }
    }
}

// ---------------------------------------------------------------------------
// Edge conv + vec_lna + mean over K neighbors -> bf16 hi/lo output (ld 256).
// fp16 AH gather (interleaved AF AD pairs); fp32 AG center terms; XCD swizzle.
// ---------------------------------------------------------------------------
template <int O, int PT>
__global__ __launch_bounds__(256, 6) void edge_kernel(const __half* __restrict__ AH,
                                                      const float* __restrict__ AG,
                                                      const int* __restrict__ idx,
                                                      unsigned short* __restrict__ outh,
                                                      unsigned short* __restrict__ outl,
                                                      int ooff)
{
    constexpr int TP = O / 2;          // threads per point
    constexpr int twoO = 2 * O;
    const int lb = xcd_swizzle(blockIdx.x, gridDim.x);
    const int tid = threadIdx.x;
    const int op = tid % TP;
    const int pt = tid / TP;
    const int gp = lb * PT + pt;
    const int b = gp >> 11;
    __shared__ int sIdx[PT][KNN_K];
    for (int j = tid; j < PT * KNN_K; j += 256)
        sIdx[j >> 4][j & 15] = idx[(lb * PT + (j >> 4)) * KNN_K + (j & 15)];
    __syncthreads();
    const int rown = gp * 3;
    const float4 c0 = *(const float4*)&AG[(size_t)(rown + 0) * twoO + 4 * op];
    const float4 c1 = *(const float4*)&AG[(size_t)(rown + 1) * twoO + 4 * op];
    const float4 c2 = *(const float4*)&AG[(size_t)(rown + 2) * twoO + 4 * op];
    float ax0 = 0.f, ax1 = 0.f, ax2 = 0.f;   // o = 2op
    float ay0 = 0.f, ay1 = 0.f, ay2 = 0.f;   // o = 2op+1
    const int bbase = (b << 11) * 3;
#pragma unroll 2
    for (int k = 0; k < KNN_K; k++) {
        int m = sIdx[pt][k];
        const __half* base = AH + (size_t)(bbase + m * 3) * twoO + 4 * op;
        uint2 u0 = *(const uint2*)(base);
        uint2 u1 = *(const uint2*)(base + twoO);
        uint2 u2 = *(const uint2*)(base + 2 * twoO);
        float2 e0 = __half22float2(*(__half2*)&u0.x);
        float2 f0 = __half22float2(*(__half2*)&u0.y);
        float2 e1 = __half22float2(*(__half2*)&u1.x);
        float2 f1 = __half22float2(*(__half2*)&u1.y);
        float2 e2 = __half22float2(*(__half2*)&u2.x);
        float2 f2 = __half22float2(*(__half2*)&u2.y);
        {
            float p0 = e0.x + c0.x, d0 = e0.y + c0.y;
            float p1 = e1.x + c1.x, d1 = e1.y + c1.y;
            float p2 = e2.x + c2.x, d2 = e2.y + c2.y;
            float dot = fmaf(p2, d2, fmaf(p1, d1, p0 * d0));
            float dsq = fmaf(d2, d2, fmaf(d1, d1, d0 * d0));
            float s = (dot < 0.f) ? 0.8f * dot / (dsq + 1e-6f) : 0.f;
            ax0 += fmaf(-s, d0, p0);
            ax1 += fmaf(-s, d1, p1);
            ax2 += fmaf(-s, d2, p2);
        }
        {
            float p0 = f0.x + c0.z, d0 = f0.y + c0.w;
            float p1 = f1.x + c1.z, d1 = f1.y + c1.w;
            float p2 = f2.x + c2.z, d2 = f2.y + c2.w;
            float dot = fmaf(p2, d2, fmaf(p1, d1, p0 * d0));
            float dsq = fmaf(d2, d2, fmaf(d1, d1, d0 * d0));
            float s = (dot < 0.f) ? 0.8f * dot / (dsq + 1e-6f) : 0.f;
            ay0 += fmaf(-s, d0, p0);
            ay1 += fmaf(-s, d1, p1);
            ay2 += fmaf(-s, d2, p2);
        }
    }
    float rx[3] = { ax0 * 0.0625f, ax1 * 0.0625f, ax2 * 0.0625f };
    float ry[3] = { ay0 * 0.0625f, ay1 * 0.0625f, ay2 * 0.0625f };
#pragma unroll
    for (int v = 0; v < 3; v++) {
        unsigned short hx, lx, hy, ly;
        split_bf16(rx[v], hx, lx);
        split_bf16(ry[v], hy, ly);
        const size_t ob = (size_t)(rown + v) * 256 + ooff + 2 * op;
        *(unsigned*)(outh + ob) = (unsigned)hx | ((unsigned)hy << 16);
        *(unsigned*)(outl + ob) = (unsigned)lx | ((unsigned)ly << 16);
    }
}

// ---------------------------------------------------------------------------
// xm: partial sums over n of xc2 (ld 128), then mean -> 12x128 bf16-pair table
// ---------------------------------------------------------------------------
__global__ void xm_partial_kernel(const unsigned short* __restrict__ xh,
                                  const unsigned short* __restrict__ xl,
                                  float* __restrict__ part)
{
    const int g = blockIdx.x;        // B*3*32 = 384
    const int s = g & 31;
    const int bv = g >> 5;           // 0..11  (b*3+v)
    const int b = bv / 3;
    const int v = bv % 3;
    const int o = threadIdx.x;       // 128
    float acc = 0.f;
    for (int i = 0; i < 64; i++) {
        int n = s * 64 + i;
        size_t ix = (size_t)((b * NPTS + n) * 3 + v) * 128 + o;
        acc += bf2(xh[ix], xl[ix]);
    }
    part[(bv * 32 + s) * 128 + o] = acc;
}

__global__ void xm_final_kernel(const float* __restrict__ part,
                                unsigned short* __restrict__ xmh,
                                unsigned short* __restrict__ xml)
{
    const int bv = blockIdx.x;       // 12
    const int o = threadIdx.x;       // 128
    float acc = 0.f;
    for (int i = 0; i < 32; i++) acc += part[(bv * 32 + i) * 128 + o];
    unsigned short h, l;
    split_bf16(acc * (1.f / 2048.f), h, l);
    xmh[bv * 128 + o] = h;
    xml[bv * 128 + o] = l;
}

// ---------------------------------------------------------------------------
// final: vec_lna(wi2 PD) fused with inv = sum_v xcat2 * x0, LDS transpose.
// xcat2 col o<128 from xc2 (ld 128); o>=128 from the 12x128 xm table.
// ---------------------------------------------------------------------------
__global__ __launch_bounds__(256) void final_inv_kernel(const float* __restrict__ PD2,
                                                        const unsigned short* __restrict__ xch,
                                                        const unsigned short* __restrict__ xcl,
                                                        const unsigned short* __restrict__ xmh,
                                                        const unsigned short* __restrict__ xml,
                                                        float* __restrict__ out)
{
    __shared__ float sh[32][257];
    const int tid = threadIdx.x;     // o = tid, 0..255
    const int base_gp = blockIdx.x * 32;
    const int b = base_gp >> 11;
    const int n0 = base_gp & (NPTS - 1);
    for (int pt = 0; pt < 32; pt++) {
        const int row = (base_gp + pt) * 3;
        float p[3], d[3], xc[3];
#pragma unroll
        for (int v = 0; v < 3; v++) {
            p[v]  = PD2[(size_t)(row + v) * 512 + tid];
            d[v]  = PD2[(size_t)(row + v) * 512 + 256 + tid];
            if (tid < 128) {
                size_t ix = (size_t)(row + v) * 128 + tid;
                xc[v] = bf2(xch[ix], xcl[ix]);
            } else {
                size_t ix = (size_t)(b * 3 + v) * 128 + tid - 128;
                xc[v] = bf2(xmh[ix], xml[ix]);
            }
        }
        float dot = fmaf(p[2], d[2], fmaf(p[1], d[1], p[0] * d[0]));
        float dsq = fmaf(d[2], d[2], fmaf(d[1], d[1], d[0] * d[0]));
        float s = (dot < 0.f) ? 0.8f * dot / (dsq + 1e-6f) : 0.f;
        float inv = 0.f;
#pragma unroll
        for (int v = 0; v < 3; v++) {
            inv = fmaf(xc[v], fmaf(-s, d[v], p[v]), inv);
        }
        sh[pt][tid] = inv;
    }
    __syncthreads();
#pragma unroll
    for (int j = 0; j < 32; j++) {
        int ow = (tid >> 5) + j * 8;
        int pt2 = tid & 31;
        out[((size_t)b * 256 + ow) * NPTS + n0 + pt2] = sh[pt2][ow];
    }
}

// ---------------------------------------------------------------------------
// launch
// ---------------------------------------------------------------------------
extern "C" void kernel_launch(void* const* d_in, const int* in_sizes, int n_in,
                              void* d_out, int out_size, void* d_ws, size_t ws_size,
                              hipStream_t stream)
{
    const float* x    = (const float*)d_in[0];
    const float* w1f  = (const float*)d_in[1];
    const float* w1d  = (const float*)d_in[2];
    const float* w2f  = (const float*)d_in[3];
    const float* w2d  = (const float*)d_in[4];
    const float* w3f  = (const float*)d_in[5];
    const float* w3d  = (const float*)d_in[6];
    const float* w4f  = (const float*)d_in[7];
    const float* w4d  = (const float*)d_in[8];
    const float* wcf  = (const float*)d_in[9];
    const float* wcd  = (const float*)d_in[10];
    const float* wi1f = (const float*)d_in[11];
    const float* wi1d = (const float*)d_in[12];
    const float* wi2f = (const float*)d_in[13];
    const float* wi2d = (const float*)d_in[14];
    float* out = (float*)d_out;

    float* F = (float*)d_ws;
    size_t off = 0;
    float* AG = F + off;                          off += (size_t)MROWS * 512;  // fp32 PD / G-half buffer
    __half* AH = (__half*)(F + off);              off += (size_t)MROWS * 128;  // fp16 A-half
    unsigned short* X240h = (unsigned short*)(F + off); off += (size_t)MROWS * 128;
    unsigned short* X240l = (unsigned short*)(F + off); off += (size_t)MROWS * 128;
    unsigned short* xc2h  = (unsigned short*)(F + off); off += (size_t)MROWS * 64;  // ld 128
    unsigned short* xc2l  = (unsigned short*)(F + off); off += (size_t)MROWS * 64;
    unsigned short* Wb2h = (unsigned short*)(F + off); off += 2048;
    unsigned short* Wb2l = (unsigned short*)(F + off); off += 2048;
    unsigned short* Wb3h = (unsigned short*)(F + off); off += 4096;
    unsigned short* Wb3l = (unsigned short*)(F + off); off += 4096;
    unsigned short* Wb4h = (unsigned short*)(F + off); off += 16384;
    unsigned short* Wb4l = (unsigned short*)(F + off); off += 16384;
    unsigned short* Wch  = (unsigned short*)(F + off); off += 24576;
    unsigned short* Wcl  = (unsigned short*)(F + off); off += 24576;
    unsigned short* Wi1h = (unsigned short*)(F + off); off += 32768;
    unsigned short* Wi1l = (unsigned short*)(F + off); off += 32768;
    unsigned short* Wi2h = (unsigned short*)(F + off); off += 32768;
    unsigned short* Wi2l = (unsigned short*)(F + off); off += 32768;
    float* part = F + off;                        off += 12 * 32 * 128;
    unsigned short* xmph = (unsigned short*)(F + off); off += 768;   // 12*128 u16
    unsigned short* xmpl = (unsigned short*)(F + off); off += 768;
    int* idx    = (int*)(F + off);                off += NBP * KNN_K;
    unsigned short* y1h = X240h;   // alias: X240 dead after wc GEMM
    unsigned short* y1l = X240l;

    // prep (layer-1 from x + all weight builds) + knn
    prep_kernel<<<(PC6 + 255) / 256, 256, 0, stream>>>(
        x, AH, AG, w1f, w1d,
        w2f, w2d, Wb2h, Wb2l, w3f, w3d, Wb3h, Wb3l, w4f, w4d, Wb4h, Wb4l,
        wcf, wcd, Wch, Wcl, wi1f, wi1d, Wi1h, Wi1l, wi2f, wi2d, Wi2h, Wi2l);
    knn_kernel<<<NBP, 64, 0, stream>>>(x, idx);

    const int GM = MROWS / 256;   // 96

    // layer 1 edge (AH/AG filled by prep)
    edge_kernel<16, 32><<<NBP / 32, 256, 0, stream>>>(AH, AG, idx, X240h, X240l, 0);
    // layer 2: K=16 (pad 32), O=32
    gemm_mfma<<<dim3(GM, 2), 256, 0, stream>>>(X240h, X240l, 256, 0, Wb2h, Wb2l, nullptr, 0, 128, 32, AH, AG, 64);
    edge_kernel<32, 16><<<NBP / 16, 256, 0, stream>>>(AH, AG, idx, X240h, X240l, 16);
    // layer 3: K=32, O=64
    gemm_mfma<<<dim3(GM, 4), 256, 0, stream>>>(X240h, X240l, 256, 16, Wb3h, Wb3l, nullptr, 0, 256, 32, AH, AG, 128);
    edge_kernel<64, 8><<<NBP / 8, 256, 0, stream>>>(AH, AG, idx, X240h, X240l, 48);
    // layer 4: K=64, O=128
    gemm_mfma<<<dim3(GM, 8), 256, 0, stream>>>(X240h, X240l, 256, 48, Wb4h, Wb4l, nullptr, 0, 512, 64, AH, AG, 256);
    edge_kernel<128, 4><<<NBP / 4, 256, 0, stream>>>(AH, AG, idx, X240h, X240l, 112);

    // wc (K=240 pad 256) fused with vec_lna -> xc2 pair (ld 128)
    gemm_lna<3, true><<<MROWS / 48, 256, 0, stream>>>(X240h, X240l, 256, nullptr, nullptr,
                                                      Wch, Wcl, 256, xc2h, xc2l);

    // xm mean -> 12x128 bf16-pair table
    xm_partial_kernel<<<BATCH * 3 * 32, 128, 0, stream>>>(xc2h, xc2l, part);
    xm_final_kernel<<<BATCH * 3, 128, 0, stream>>>(part, xmph, xmpl);

    // wi1 (K=256: k<128 from xc2, k>=128 from xm table) fused with vec_lna -> y1
    gemm_lna<4, false><<<MROWS / 48, 256, 0, stream>>>(xc2h, xc2l, 128, xmph, xmpl,
                                                       Wi1h, Wi1l, 256, y1h, y1l);

    // wi2: K=128 -> PD [MROWS,512] -> fused lna + inv + transpose
    gemm_mfma<<<dim3(GM, 8), 256, 0, stream>>>(y1h, y1l, 128, 0, Wi2h, Wi2l, AG, 512, 512, 128, nullptr, nullptr, 0);
    final_inv_kernel<<<NBP / 32, 256, 0, stream>>>(AG, xc2h, xc2l, xmph, xmpl, out);

    (void)in_sizes; (void)n_in; (void)out_size; (void)ws_size;
}